// Round 5
// baseline (127.538 us; speedup 1.0000x reference)
//
#include <hip/hip_runtime.h>
#include <math.h>

// GMM score, rescaled: out_j = (E_w[td] - x_j) / sigma2_j
// w_i = exp(-0.5 (td_i - x_j)^2 / sigma2_j), sigma2_j = (exp(2 t_j ln25)-1)/(2 ln25)
//
// B = N = 16384, d = 1. exp-pipe bound: 268M v_exp_f32, minimal mix is
// 2 pk-VALU + 1 exp per pair. R4 showed 36% issue-stall at 64% VALUBusy.
// R5: attack the stall:
//  - software-pipelined s_load_dwordx8 (prefetch next 8-elem group before
//    processing current -> lgkm wait overlaps ~48 VALU/exp issues)
//  - 4 j's per thread (CH=128, S=128): each scalar load feeds 4 outputs,
//    32 independent exp/acc chains. Grid (16,128)=2048 blocks = 8 blocks/CU
//    = 32 waves/CU, single generation (no block churn).

typedef float v2f __attribute__((ext_vector_type(2)));
typedef float v8f __attribute__((ext_vector_type(8)));

#define BLK 256
#define CH  128          // i's per slice
#define JPT 4            // j's per thread
#define JPB (JPT * BLK)  // j's per block

#if __has_builtin(__builtin_amdgcn_exp2f)
#define EXP2(x) __builtin_amdgcn_exp2f(x)
#else
#define EXP2(x) exp2f(x)
#endif

__device__ __forceinline__ float sigma2_of(float tj) {
  const float TWO_LOG_S = 6.4377516497364011f;   // 2*ln(25)
  return (__expf(TWO_LOG_S * tj) - 1.0f) / TWO_LOG_S;
}

template <bool ATOMIC>
__launch_bounds__(BLK)
__global__ void gmm_partial(const float* __restrict__ x,
                            const float* __restrict__ t,
                            const float* __restrict__ td,
                            float* __restrict__ ws,
                            int N, int B) {
  const int tid  = threadIdx.x;
  const int s    = blockIdx.y;               // N-slice
  const int S    = gridDim.y;
  const int base = s * CH;
  const float* __restrict__ tp = td + base;

  const float HALF_LOG2E = 0.72134752044448170f;   // 0.5 * log2(e)
  int   j[JPT];
  v2f   rv[JPT], ny[JPT];
  #pragma unroll
  for (int k = 0; k < JPT; ++k) {
    j[k] = blockIdx.x * JPB + k * BLK + tid;       // coalesced per wave
    float r = 0.f, y = 0.f;
    if (j[k] < B) {
      r = __fsqrt_rn(HALF_LOG2E / sigma2_of(t[j[k]]));
      y = x[j[k]] * r;
    }
    rv[k].x = r;  rv[k].y = r;
    ny[k].x = -y; ny[k].y = -y;
  }

  // 2 chains per j -> 8 v2f accumulators per j-pairstream, 32 total chains
  v2f nacc[JPT][2], dacc[JPT][2];
  #pragma unroll
  for (int k = 0; k < JPT; ++k)
    #pragma unroll
    for (int c = 0; c < 2; ++c) {
      nacc[k][c].x = 0.f; nacc[k][c].y = 0.f;
      dacc[k][c].x = 0.f; dacc[k][c].y = 0.f;
    }

  auto proc8 = [&](v8f f) {
    v2f g[4] = {{f[0], f[1]}, {f[2], f[3]}, {f[4], f[5]}, {f[6], f[7]}};
    #pragma unroll
    for (int u = 0; u < 4; ++u) {
      #pragma unroll
      for (int k = 0; k < JPT; ++k) {
        v2f d = __builtin_elementwise_fma(g[u], rv[k], ny[k]);  // v_pk_fma_f32
        v2f q = d * d;                                          // v_pk_mul_f32
        v2f p;
        p.x = EXP2(-q.x);                                       // v_exp_f32
        p.y = EXP2(-q.y);
        dacc[k][u & 1] += p;                                    // v_pk_add_f32
        nacc[k][u & 1] = __builtin_elementwise_fma(p, g[u], nacc[k][u & 1]);
      }
    }
  };

  const int lim = (N - base < CH) ? (N - base) : CH;   // CH when N%CH==0
  if (lim == CH) {
    // software pipeline: prefetch group i+8 before processing group i
    v8f f = *(const v8f*)(tp);
    for (int i = 0; i < CH - 8; i += 8) {
      v8f fn = *(const v8f*)(tp + i + 8);
      proc8(f);
      f = fn;
    }
    proc8(f);
  } else {
    for (int i = 0; i < lim; i += 8) {
      v8f f;
      #pragma unroll
      for (int e = 0; e < 8; ++e) f[e] = (i + e < lim) ? tp[i + e] : 1e30f;
      proc8(f);
    }
  }

  #pragma unroll
  for (int k = 0; k < JPT; ++k) {
    v2f nv = nacc[k][0] + nacc[k][1];
    v2f dv = dacc[k][0] + dacc[k][1];
    float num = nv.x + nv.y;
    float den = dv.x + dv.y;
    if (j[k] < B) {
      if (ATOMIC) {
        atomicAdd(&ws[j[k]], num);
        atomicAdd(&ws[B + j[k]], den);
      } else {
        ws[(size_t)s * B + j[k]]       = num;   // num partials: [S][B]
        ws[(size_t)(S + s) * B + j[k]] = den;   // den partials: [S][B]
      }
    }
  }
}

__global__ void gmm_final(const float* __restrict__ x,
                          const float* __restrict__ t,
                          const float* __restrict__ ws,
                          float* __restrict__ out, int B, int S) {
  int j = blockIdx.x * blockDim.x + threadIdx.x;
  if (j >= B) return;
  float num = 0.f, den = 0.f;
  for (int s = 0; s < S; ++s) {
    num += ws[(size_t)s * B + j];
    den += ws[(size_t)(S + s) * B + j];
  }
  float sigma2 = sigma2_of(t[j]);
  float evals = (den == 0.0f) ? 0.0f : (num / den);   // reference's den==0 guard
  out[j] = (evals - x[j]) / sigma2;
}

__global__ void zero_kernel(float* __restrict__ p, int n) {
  int i = blockIdx.x * blockDim.x + threadIdx.x;
  if (i < n) p[i] = 0.0f;
}

extern "C" void kernel_launch(void* const* d_in, const int* in_sizes, int n_in,
                              void* d_out, int out_size, void* d_ws, size_t ws_size,
                              hipStream_t stream) {
  const float* x  = (const float*)d_in[0];
  const float* t  = (const float*)d_in[1];
  const float* td = (const float*)d_in[2];
  float* out = (float*)d_out;
  float* ws  = (float*)d_ws;

  const int B = in_sizes[0];
  const int N = in_sizes[2];

  const int S = (N + CH - 1) / CH;                  // 128 for N=16384
  size_t need = (size_t)2 * S * B * sizeof(float);  // 16 MB

  if (ws_size >= need) {
    dim3 grid((B + JPB - 1) / JPB, S);              // (16, 128) = 2048 blocks
    gmm_partial<false><<<grid, BLK, 0, stream>>>(x, t, td, ws, N, B);
    gmm_final<<<(B + BLK - 1) / BLK, BLK, 0, stream>>>(x, t, ws, out, B, S);
  } else {
    // Fallback: zero + atomic accumulate + final (3 dispatches)
    int nzero = 2 * B;
    zero_kernel<<<(nzero + 255) / 256, 256, 0, stream>>>(ws, nzero);
    dim3 grid((B + JPB - 1) / JPB, S);
    gmm_partial<true><<<grid, BLK, 0, stream>>>(x, t, td, ws, N, B);
    gmm_final<<<(B + BLK - 1) / BLK, BLK, 0, stream>>>(x, t, ws, out, B, 1);
  }
}

// Round 6
// 92.512 us; speedup vs baseline: 1.3786x; 1.3786x over previous
//
#include <hip/hip_runtime.h>
#include <math.h>

// GMM score, rescaled: out_j = (E_w[td] - x_j) / sigma2_j
// w_i = exp(-0.5 (td_i - x_j)^2 / sigma2_j), sigma2_j = (exp(2 t_j ln25)-1)/(2 ln25)
//
// Timing model (fitted R1-R5): dur = 43.5us harness ws-poison (fixed)
//   + gmm_partial + gmm_final + ~4us gaps.
// gmm_partial is at ~85% of its serial-issue floor (per v2f: 4 pk-VALU @2cyc
// + 2 v_exp_f32 @16cyc -> 34.1us model, 40.0us measured) -- structural.
// R6: revert partial to the proven R3 config (LDS, S=32, 40.0us) and make the
// final reduction PARALLEL (R5's serial final cost 0.35us/slice and caused the
// regression): 512 blocks x (32 j x 8 slice-groups), 4 coalesced loads/thread,
// LDS combine. Est ~3us.

typedef float v2f __attribute__((ext_vector_type(2)));

#define BLK   256
#define CH    512    // train elements per slice (2 KB LDS); S = N/CH = 32

#if __has_builtin(__builtin_amdgcn_exp2f)
#define EXP2(x) __builtin_amdgcn_exp2f(x)
#else
#define EXP2(x) exp2f(x)
#endif

__device__ __forceinline__ float sigma2_of(float tj) {
  const float TWO_LOG_S = 6.4377516497364011f;   // 2*ln(25)
  return (__expf(TWO_LOG_S * tj) - 1.0f) / TWO_LOG_S;
}

template <bool ATOMIC>
__launch_bounds__(BLK)
__global__ void gmm_partial(const float* __restrict__ x,
                            const float* __restrict__ t,
                            const float* __restrict__ td,
                            float* __restrict__ ws,
                            int N, int B) {
  __shared__ float lds[CH];
  const int tid  = threadIdx.x;
  const int j    = blockIdx.x * BLK + tid;   // output index
  const int s    = blockIdx.y;               // N-slice
  const int S    = gridDim.y;
  const int base = s * CH;

  for (int i = tid; i < CH; i += BLK) {
    int gi = base + i;
    // pad -> d^2 = inf -> exp2(-inf) = 0 (weightless)
    lds[i] = (gi < N) ? td[gi] : 1e30f;
  }

  float r = 0.0f, y = 0.0f;
  if (j < B) {
    const float HALF_LOG2E = 0.72134752044448170f;  // 0.5 * log2(e)
    float s2 = sigma2_of(t[j]);
    r = __fsqrt_rn(HALF_LOG2E / s2);   // d = (td - x)*r ; arg = -d^2
    y = x[j] * r;
  }
  __syncthreads();

  const v2f rv  = {r, r};
  const v2f nyv = {-y, -y};
  v2f num0 = {0.f, 0.f}, num1 = {0.f, 0.f}, num2 = {0.f, 0.f}, num3 = {0.f, 0.f};
  v2f den0 = {0.f, 0.f}, den1 = {0.f, 0.f}, den2 = {0.f, 0.f}, den3 = {0.f, 0.f};

  const float4* l4 = (const float4*)lds;   // ds_read_b128 broadcast, conflict-free
  const int iters = CH >> 3;               // 8 elements per iteration
  #pragma unroll 2
  for (int i = 0; i < iters; ++i) {
    float4 v0 = l4[2 * i];
    float4 v1 = l4[2 * i + 1];
    v2f va = {v0.x, v0.y}, vb = {v0.z, v0.w};
    v2f vc = {v1.x, v1.y}, vd = {v1.z, v1.w};
    // d = td*r - x*r   (one v_pk_fma_f32)
    v2f da = __builtin_elementwise_fma(va, rv, nyv);
    v2f db = __builtin_elementwise_fma(vb, rv, nyv);
    v2f dc = __builtin_elementwise_fma(vc, rv, nyv);
    v2f dd = __builtin_elementwise_fma(vd, rv, nyv);
    v2f qa = da * da;   // v_pk_mul_f32
    v2f qb = db * db;
    v2f qc = dc * dc;
    v2f qd = dd * dd;
    v2f pa, pb, pc, pd;
    pa.x = EXP2(-qa.x); pa.y = EXP2(-qa.y);   // v_exp_f32, neg input mod
    pb.x = EXP2(-qb.x); pb.y = EXP2(-qb.y);
    pc.x = EXP2(-qc.x); pc.y = EXP2(-qc.y);
    pd.x = EXP2(-qd.x); pd.y = EXP2(-qd.y);
    den0 += pa;                                       // v_pk_add_f32
    den1 += pb;
    den2 += pc;
    den3 += pd;
    num0 = __builtin_elementwise_fma(pa, va, num0);   // v_pk_fma_f32
    num1 = __builtin_elementwise_fma(pb, vb, num1);
    num2 = __builtin_elementwise_fma(pc, vc, num2);
    num3 = __builtin_elementwise_fma(pd, vd, num3);
  }
  v2f numv = (num0 + num1) + (num2 + num3);
  v2f denv = (den0 + den1) + (den2 + den3);
  float num = numv.x + numv.y;
  float den = denv.x + denv.y;

  if (j < B) {
    if (ATOMIC) {
      atomicAdd(&ws[j], num);
      atomicAdd(&ws[B + j], den);
    } else {
      ws[(size_t)s * B + j]       = num;   // num partials: [S][B]
      ws[(size_t)(S + s) * B + j] = den;   // den partials: [S][B]
    }
  }
}

// Parallel final reduction: block = 32 j's x 8 slice-groups; each thread sums
// slices s = g, g+8, g+16, ... (coalesced across the 32 j-lanes), then LDS
// combine over the 8 groups and epilogue. Grid = ceil(B/32) blocks.
#define FJ 32   // j's per final block
#define FG 8    // slice-groups per final block
__launch_bounds__(FJ * FG)
__global__ void gmm_final(const float* __restrict__ x,
                          const float* __restrict__ t,
                          const float* __restrict__ ws,
                          float* __restrict__ out, int B, int S) {
  __shared__ float nbuf[FG * FJ];
  __shared__ float dbuf[FG * FJ];
  const int tid = threadIdx.x;
  const int jl  = tid & (FJ - 1);     // j lane
  const int g   = tid >> 5;           // slice group
  const int j   = blockIdx.x * FJ + jl;

  float np = 0.f, dp = 0.f;
  if (j < B) {
    for (int s = g; s < S; s += FG) {
      np += ws[(size_t)s * B + j];
      dp += ws[(size_t)(S + s) * B + j];
    }
  }
  nbuf[tid] = np;
  dbuf[tid] = dp;
  __syncthreads();

  if (g == 0 && j < B) {
    float num = 0.f, den = 0.f;
    #pragma unroll
    for (int gg = 0; gg < FG; ++gg) {
      num += nbuf[gg * FJ + jl];
      den += dbuf[gg * FJ + jl];
    }
    float sigma2 = sigma2_of(t[j]);
    float evals = (den == 0.0f) ? 0.0f : (num / den);   // reference's den==0 guard
    out[j] = (evals - x[j]) / sigma2;
  }
}

__global__ void gmm_final_serial(const float* __restrict__ x,
                                 const float* __restrict__ t,
                                 const float* __restrict__ ws,
                                 float* __restrict__ out, int B, int S) {
  int j = blockIdx.x * blockDim.x + threadIdx.x;
  if (j >= B) return;
  float num = 0.f, den = 0.f;
  for (int s = 0; s < S; ++s) {
    num += ws[(size_t)s * B + j];
    den += ws[(size_t)(S + s) * B + j];
  }
  float sigma2 = sigma2_of(t[j]);
  float evals = (den == 0.0f) ? 0.0f : (num / den);
  out[j] = (evals - x[j]) / sigma2;
}

__global__ void zero_kernel(float* __restrict__ p, int n) {
  int i = blockIdx.x * blockDim.x + threadIdx.x;
  if (i < n) p[i] = 0.0f;
}

extern "C" void kernel_launch(void* const* d_in, const int* in_sizes, int n_in,
                              void* d_out, int out_size, void* d_ws, size_t ws_size,
                              hipStream_t stream) {
  const float* x  = (const float*)d_in[0];
  const float* t  = (const float*)d_in[1];
  const float* td = (const float*)d_in[2];
  float* out = (float*)d_out;
  float* ws  = (float*)d_ws;

  const int B = in_sizes[0];
  const int N = in_sizes[2];

  const int S = (N + CH - 1) / CH;                  // 32 for N=16384
  size_t need = (size_t)2 * S * B * sizeof(float);  // 4 MB

  if (ws_size >= need) {
    dim3 grid((B + BLK - 1) / BLK, S);              // (64, 32) = 2048 blocks
    gmm_partial<false><<<grid, BLK, 0, stream>>>(x, t, td, ws, N, B);
    gmm_final<<<(B + FJ - 1) / FJ, FJ * FG, 0, stream>>>(x, t, ws, out, B, S);
  } else {
    // Fallback: zero + atomic accumulate + serial final (3 dispatches)
    int nzero = 2 * B;
    zero_kernel<<<(nzero + 255) / 256, 256, 0, stream>>>(ws, nzero);
    dim3 grid((B + BLK - 1) / BLK, S);
    gmm_partial<true><<<grid, BLK, 0, stream>>>(x, t, td, ws, N, B);
    gmm_final_serial<<<(B + 255) / 256, 256, 0, stream>>>(x, t, ws, out, B, 1);
  }
}